// Round 5
// baseline (573.662 us; speedup 1.0000x reference)
//
#include <hip/hip_runtime.h>
#include <hip/hip_bf16.h>

#define BB 4
#define SS 2048
#define DD 1024
#define HH 16
#define DHH 64
#define MM (BB*SS)   // 8192

typedef __bf16 bf16;
typedef __attribute__((ext_vector_type(8))) __bf16 bf16x8;
typedef __attribute__((ext_vector_type(4))) float floatx4;

// ------------------------------------------------------------ transpose
// Wt[n][k] = (bf16)W[k][n], W is f32 1024x1024; four matrices via blockIdx.z
__global__ void transpose_k(const float* __restrict__ W0, const float* __restrict__ W1,
                            const float* __restrict__ W2, const float* __restrict__ W3,
                            bf16* __restrict__ Wt) {
    __shared__ bf16 tile[64][65];
    const float* W = (blockIdx.z == 0) ? W0 : (blockIdx.z == 1) ? W1
                    : (blockIdx.z == 2) ? W2 : W3;
    bf16* Wo = Wt + (size_t)blockIdx.z * DD * DD;
    int bx = blockIdx.x * 64, by = blockIdx.y * 64;
    int tx = threadIdx.x & 63, ty = threadIdx.x >> 6;
    for (int i = ty; i < 64; i += 4)
        tile[i][tx] = (bf16)W[(size_t)(by + i) * DD + bx + tx];
    __syncthreads();
    for (int i = ty; i < 64; i += 4)
        Wo[(size_t)(bx + i) * DD + by + tx] = tile[tx][i];
}

// ------------------------------------------------------------ GEMM
// out = A[m][k] * Bt[n][k] + bias[n];  A is f32 if AF32 else bf16
// MODE 0: float out[m*DD+n]
// MODE 1: bf16  out[((b*H+h)*S+s)*DH+dh]
// MODE 2: bf16  out[((b*H+h)*DH+dh)*S+s]
template<int MODE, int AF32>
__global__ __launch_bounds__(256) void gemm_k(const void* __restrict__ Av,
                                              const bf16* __restrict__ Bt,
                                              const float* __restrict__ bias,
                                              void* __restrict__ outv) {
    __shared__ __align__(16) bf16 la[64 * 40];
    __shared__ __align__(16) bf16 lb[64 * 40];
    const int tid = threadIdx.x;
    const int l = tid & 63, w = tid >> 6;
    const int quad = l >> 4, lane16 = l & 15;
    const int m0 = blockIdx.y * 64, n0 = blockIdx.x * 64;
    const int row = tid >> 2, col8 = (tid & 3) * 8;

    floatx4 acc[4] = {};
    for (int k0 = 0; k0 < DD; k0 += 32) {
        if (AF32) {
            const float* Ap = (const float*)Av + (size_t)(m0 + row) * DD + k0 + col8;
            float4 f0 = *(const float4*)Ap;
            float4 f1 = *(const float4*)(Ap + 4);
            bf16x8 v;
            v[0] = (bf16)f0.x; v[1] = (bf16)f0.y; v[2] = (bf16)f0.z; v[3] = (bf16)f0.w;
            v[4] = (bf16)f1.x; v[5] = (bf16)f1.y; v[6] = (bf16)f1.z; v[7] = (bf16)f1.w;
            *(bf16x8*)(la + row * 40 + col8) = v;
        } else {
            *(uint4*)(la + row * 40 + col8) =
                *(const uint4*)((const bf16*)Av + (size_t)(m0 + row) * DD + k0 + col8);
        }
        *(uint4*)(lb + row * 40 + col8) =
            *(const uint4*)(Bt + (size_t)(n0 + row) * DD + k0 + col8);
        __syncthreads();
        bf16x8 af = *(const bf16x8*)(la + (w * 16 + lane16) * 40 + quad * 8);
#pragma unroll
        for (int nb = 0; nb < 4; nb++) {
            bf16x8 bfr = *(const bf16x8*)(lb + (nb * 16 + lane16) * 40 + quad * 8);
            acc[nb] = __builtin_amdgcn_mfma_f32_16x16x32_bf16(af, bfr, acc[nb], 0, 0, 0);
        }
        __syncthreads();
    }
#pragma unroll
    for (int nb = 0; nb < 4; nb++) {
#pragma unroll
        for (int r = 0; r < 4; r++) {
            int m = m0 + w * 16 + quad * 4 + r;
            int n = n0 + nb * 16 + lane16;
            float v = acc[nb][r] + bias[n];
            if (MODE == 0) {
                ((float*)outv)[(size_t)m * DD + n] = v;          // f32 final output
            } else {
                int b = m >> 11, s = m & (SS - 1);
                int h = n >> 6, dh = n & 63;
                if (MODE == 1)
                    ((bf16*)outv)[((size_t)(b * HH + h) * SS + s) * DHH + dh] = (bf16)v;
                else
                    ((bf16*)outv)[((size_t)(b * HH + h) * DHH + dh) * SS + s] = (bf16)v;
            }
        }
    }
}

// ------------------------------------------------------------ attention
// Q,K: [bh][s][dh]   Vt: [bh][dh][s]   ctx: [b][s][h*DH+dh]
__global__ __launch_bounds__(256) void attn_k(const bf16* __restrict__ Q,
                                              const bf16* __restrict__ K,
                                              const bf16* __restrict__ Vt,
                                              bf16* __restrict__ ctx) {
    __shared__ __align__(16) bf16 qs[64 * 72];
    __shared__ __align__(16) bf16 ks[64 * 72];
    __shared__ __align__(16) bf16 vs[64 * 72];
    __shared__ __align__(16) bf16 ps[4][16 * 72];

    const int tid = threadIdx.x;
    const int l = tid & 63, w = tid >> 6;
    const int quad = l >> 4, lane16 = l & 15;
    const int qt = blockIdx.x, bh = blockIdx.y;
    const int q0 = qt * 64;
    const bf16* Qp = Q  + (size_t)bh * SS * DHH;
    const bf16* Kp = K  + (size_t)bh * SS * DHH;
    const bf16* Vp = Vt + (size_t)bh * DHH * SS;

    {
        int row = tid >> 2, col = (tid & 3) * 16;
        *(uint4*)(qs + row * 72 + col)     = *(const uint4*)(Qp + (size_t)(q0 + row) * DHH + col);
        *(uint4*)(qs + row * 72 + col + 8) = *(const uint4*)(Qp + (size_t)(q0 + row) * DHH + col + 8);
    }

    floatx4 o_acc[4] = {};
    float m_i[4], l_i[4];
#pragma unroll
    for (int r = 0; r < 4; r++) { m_i[r] = -1e30f; l_i[r] = 0.f; }

    const float scale = 0.125f;  // 1/sqrt(64)
    const float LOG2E = 1.4426950408889634f;

    for (int kt = 0; kt <= qt; kt++) {
        __syncthreads();
        {
            int row = tid >> 2, col = (tid & 3) * 16;
            *(uint4*)(ks + row * 72 + col)     = *(const uint4*)(Kp + (size_t)(kt * 64 + row) * DHH + col);
            *(uint4*)(ks + row * 72 + col + 8) = *(const uint4*)(Kp + (size_t)(kt * 64 + row) * DHH + col + 8);
            *(uint4*)(vs + row * 72 + col)     = *(const uint4*)(Vp + (size_t)row * SS + kt * 64 + col);
            *(uint4*)(vs + row * 72 + col + 8) = *(const uint4*)(Vp + (size_t)row * SS + kt * 64 + col + 8);
        }
        __syncthreads();

        floatx4 sc[4] = {};
#pragma unroll
        for (int kk = 0; kk < 2; kk++) {
            bf16x8 af = *(const bf16x8*)(qs + (w * 16 + lane16) * 72 + kk * 32 + quad * 8);
#pragma unroll
            for (int nb = 0; nb < 4; nb++) {
                bf16x8 bfr = *(const bf16x8*)(ks + (nb * 16 + lane16) * 72 + kk * 32 + quad * 8);
                sc[nb] = __builtin_amdgcn_mfma_f32_16x16x32_bf16(af, bfr, sc[nb], 0, 0, 0);
            }
        }

        float pv[4][4];
        float mnew[4];
#pragma unroll
        for (int r = 0; r < 4; r++) mnew[r] = -1e30f;
#pragma unroll
        for (int nb = 0; nb < 4; nb++) {
            int key = kt * 64 + nb * 16 + lane16;
#pragma unroll
            for (int r = 0; r < 4; r++) {
                int qrow = q0 + w * 16 + quad * 4 + r;
                float v = sc[nb][r] * scale;
                v = (key <= qrow) ? v : -1e30f;
                pv[nb][r] = v;
                mnew[r] = fmaxf(mnew[r], v);
            }
        }
#pragma unroll
        for (int off = 1; off < 16; off <<= 1)
#pragma unroll
            for (int r = 0; r < 4; r++)
                mnew[r] = fmaxf(mnew[r], __shfl_xor(mnew[r], off, 64));

        float alpha[4], lsum[4];
#pragma unroll
        for (int r = 0; r < 4; r++) {
            float mi = fmaxf(m_i[r], mnew[r]);
            alpha[r] = exp2f((m_i[r] - mi) * LOG2E);
            m_i[r] = mi;
            float s_ = 0.f;
#pragma unroll
            for (int nb = 0; nb < 4; nb++) {
                float p = exp2f((pv[nb][r] - mi) * LOG2E);
                pv[nb][r] = p;
                s_ += p;
            }
            lsum[r] = s_;
        }
#pragma unroll
        for (int off = 1; off < 16; off <<= 1)
#pragma unroll
            for (int r = 0; r < 4; r++)
                lsum[r] += __shfl_xor(lsum[r], off, 64);
#pragma unroll
        for (int r = 0; r < 4; r++)
            l_i[r] = l_i[r] * alpha[r] + lsum[r];
#pragma unroll
        for (int nb = 0; nb < 4; nb++)
#pragma unroll
            for (int r = 0; r < 4; r++)
                o_acc[nb][r] *= alpha[r];
#pragma unroll
        for (int nb = 0; nb < 4; nb++)
#pragma unroll
            for (int r = 0; r < 4; r++)
                ps[w][(quad * 4 + r) * 72 + nb * 16 + lane16] = (bf16)pv[nb][r];
        __syncthreads();
#pragma unroll
        for (int kk = 0; kk < 2; kk++) {
            bf16x8 af = *(const bf16x8*)(&ps[w][lane16 * 72 + kk * 32 + quad * 8]);
#pragma unroll
            for (int nb = 0; nb < 4; nb++) {
                bf16x8 bfr = *(const bf16x8*)(vs + (nb * 16 + lane16) * 72 + kk * 32 + quad * 8);
                o_acc[nb] = __builtin_amdgcn_mfma_f32_16x16x32_bf16(af, bfr, o_acc[nb], 0, 0, 0);
            }
        }
    }

    int b = bh >> 4, h = bh & 15;
#pragma unroll
    for (int r = 0; r < 4; r++) {
        float inv = 1.0f / l_i[r];
        int s = q0 + w * 16 + quad * 4 + r;
#pragma unroll
        for (int nb = 0; nb < 4; nb++) {
            int dh = nb * 16 + lane16;
            ctx[((size_t)(b * SS + s)) * DD + h * DHH + dh] = (bf16)(o_acc[nb][r] * inv);
        }
    }
}

// ------------------------------------------------------------ launch
extern "C" void kernel_launch(void* const* d_in, const int* in_sizes, int n_in,
                              void* d_out, int out_size, void* d_ws, size_t ws_size,
                              hipStream_t stream) {
    const float* x  = (const float*)d_in[0];
    const float* Wq = (const float*)d_in[1];
    const float* bq = (const float*)d_in[2];
    const float* Wk = (const float*)d_in[3];
    const float* bk = (const float*)d_in[4];
    const float* Wv = (const float*)d_in[5];
    const float* bv = (const float*)d_in[6];
    const float* Wo = (const float*)d_in[7];
    const float* bo = (const float*)d_in[8];

    // ws layout (72 MB + 256 B total):
    bf16* Wqt = (bf16*)((char*)d_ws + 256);    // 4 x 2 MB transposed bf16 weights
    bf16* Wkt = Wqt + (size_t)DD * DD;
    bf16* Wvt = Wkt + (size_t)DD * DD;
    bf16* Wot = Wvt + (size_t)DD * DD;
    bf16* Qb  = Wot + (size_t)DD * DD;         // 4 x 16 MB bf16
    bf16* Kb  = Qb + (size_t)MM * DD;
    bf16* Vb  = Kb + (size_t)MM * DD;
    bf16* Cb  = Vb + (size_t)MM * DD;

    transpose_k<<<dim3(16, 16, 4), dim3(256), 0, stream>>>(Wq, Wk, Wv, Wo, Wqt);

    dim3 gg(DD / 64, MM / 64);
    gemm_k<1, 1><<<gg, dim3(256), 0, stream>>>(x, Wqt, bq, Qb);
    gemm_k<1, 1><<<gg, dim3(256), 0, stream>>>(x, Wkt, bk, Kb);
    gemm_k<2, 1><<<gg, dim3(256), 0, stream>>>(x, Wvt, bv, Vb);
    attn_k<<<dim3(SS / 64, BB * HH), dim3(256), 0, stream>>>(Qb, Kb, Vb, Cb);
    gemm_k<0, 0><<<gg, dim3(256), 0, stream>>>(Cb, Wot, bo, d_out);
}

// Round 6
// 368.830 us; speedup vs baseline: 1.5554x; 1.5554x over previous
//
#include <hip/hip_runtime.h>
#include <hip/hip_bf16.h>

#define BB 4
#define SS 2048
#define DD 1024
#define HH 16
#define DHH 64
#define MM (BB*SS)   // 8192

typedef __bf16 bf16;
typedef __attribute__((ext_vector_type(8))) __bf16 bf16x8;
typedef __attribute__((ext_vector_type(4))) float floatx4;

#define C_SCALE 0.1803368801111164f   // 0.125 * log2(e), folded into Wq/bq

// async global->LDS DMA, 16 B per lane, lands at wave-uniform base + lane*16
#define GLD16(g, l) __builtin_amdgcn_global_load_lds( \
    (__attribute__((address_space(1))) void*)(g), \
    (__attribute__((address_space(3))) void*)(l), 16, 0, 0)

// ------------------------------------------------------------ x f32 -> bf16
__global__ __launch_bounds__(256) void cvt_k(const float* __restrict__ x,
                                             bf16* __restrict__ xc) {
    size_t o = ((size_t)blockIdx.x * 256 + threadIdx.x) * 8;
    float4 f0 = *(const float4*)(x + o);
    float4 f1 = *(const float4*)(x + o + 4);
    bf16x8 v;
    v[0] = (bf16)f0.x; v[1] = (bf16)f0.y; v[2] = (bf16)f0.z; v[3] = (bf16)f0.w;
    v[4] = (bf16)f1.x; v[5] = (bf16)f1.y; v[6] = (bf16)f1.z; v[7] = (bf16)f1.w;
    *(bf16x8*)(xc + o) = v;
}

// ------------------------------------------------------------ transpose
// Wt[z][n][k] = (bf16)(W[k][n] * scale), scale folds C_SCALE into Wq (z==0)
__global__ void transpose_k(const float* __restrict__ W0, const float* __restrict__ W1,
                            const float* __restrict__ W2, const float* __restrict__ W3,
                            bf16* __restrict__ Wt) {
    __shared__ bf16 tile[64][65];
    const float* W = (blockIdx.z == 0) ? W0 : (blockIdx.z == 1) ? W1
                    : (blockIdx.z == 2) ? W2 : W3;
    float sc = (blockIdx.z == 0) ? C_SCALE : 1.0f;
    bf16* Wo = Wt + (size_t)blockIdx.z * DD * DD;
    int bx = blockIdx.x * 64, by = blockIdx.y * 64;
    int tx = threadIdx.x & 63, ty = threadIdx.x >> 6;
    for (int i = ty; i < 64; i += 4)
        tile[i][tx] = (bf16)(W[(size_t)(by + i) * DD + bx + tx] * sc);
    __syncthreads();
    for (int i = ty; i < 64; i += 4)
        Wo[(size_t)(bx + i) * DD + by + tx] = tile[tx][i];
}

// ------------------------------------------------------------ bias concat (scale bq)
__global__ void bias_cat_k(const float* __restrict__ bq, const float* __restrict__ bk,
                           const float* __restrict__ bv, float* __restrict__ bcat) {
    int i = blockIdx.x * 256 + threadIdx.x;
    float v;
    if (i < 1024)      v = bq[i] * C_SCALE;
    else if (i < 2048) v = bk[i - 1024];
    else               v = bv[i - 2048];
    bcat[i] = v;
}

// ------------------------------------------------------------ 128x128 GEMM (m97 structure)
// out = A[m][k] * Bt[n][k] + bias[n]
// MODE 0: float out[m*DD+n]
// MODE 1: fused QKV routing; out3 base of contiguous Qb|Kb|Vb; block-uniform which=n0>>10
//   Q,K: bf16 [((b*H+h)*S+s)*DH+dh]   V: bf16 [((b*H+h)*DH+dh)*S+s]
template<int MODE>
__global__ __launch_bounds__(256) void gemm128_k(const bf16* __restrict__ A,
                                                 const bf16* __restrict__ Bt,
                                                 const float* __restrict__ bias,
                                                 void* __restrict__ outv) {
    __shared__ __align__(16) bf16 la[128 * 32];
    __shared__ __align__(16) bf16 lb[128 * 32];
    const int tid = threadIdx.x;
    const int l = tid & 63, w = tid >> 6;
    const int quad = l >> 4, lane16 = l & 15;
    const int wm = w >> 1, wn = w & 1;
    const int m0 = blockIdx.y * 128, n0 = blockIdx.x * 128;

    // staging coords: wave w, instr j covers LDS bytes (j*4+w)*1024 + lane*16
    const int sr  = l >> 2;          // row within 16-row group
    const int sc8 = (l & 3) * 8;     // elem col within 32
    const bf16* Ag0 = A  + (size_t)(m0 + w * 16 + sr) * DD + sc8;
    const bf16* Ag1 = A  + (size_t)(m0 + (4 + w) * 16 + sr) * DD + sc8;
    const bf16* Bg0 = Bt + (size_t)(n0 + w * 16 + sr) * DD + sc8;
    const bf16* Bg1 = Bt + (size_t)(n0 + (4 + w) * 16 + sr) * DD + sc8;
    bf16* Al0 = la + (size_t)(w * 16 + sr) * 32 + sc8;
    bf16* Al1 = la + (size_t)((4 + w) * 16 + sr) * 32 + sc8;
    bf16* Bl0 = lb + (size_t)(w * 16 + sr) * 32 + sc8;
    bf16* Bl1 = lb + (size_t)((4 + w) * 16 + sr) * 32 + sc8;

    floatx4 acc[4][4] = {};
    for (int k0 = 0; k0 < DD; k0 += 32) {
        __syncthreads();                       // prev iter's LDS reads done
        GLD16(Ag0 + k0, Al0);
        GLD16(Ag1 + k0, Al1);
        GLD16(Bg0 + k0, Bl0);
        GLD16(Bg1 + k0, Bl1);
        __syncthreads();                       // implicit vmcnt(0): DMA landed
        bf16x8 af[4], bfr[4];
#pragma unroll
        for (int mt = 0; mt < 4; mt++)
            af[mt] = *(const bf16x8*)(la + (size_t)(wm * 64 + mt * 16 + lane16) * 32 + quad * 8);
#pragma unroll
        for (int nt = 0; nt < 4; nt++)
            bfr[nt] = *(const bf16x8*)(lb + (size_t)(wn * 64 + nt * 16 + lane16) * 32 + quad * 8);
#pragma unroll
        for (int mt = 0; mt < 4; mt++)
#pragma unroll
            for (int nt = 0; nt < 4; nt++)
                acc[mt][nt] = __builtin_amdgcn_mfma_f32_16x16x32_bf16(af[mt], bfr[nt], acc[mt][nt], 0, 0, 0);
    }

    if (MODE == 0) {
        float* out = (float*)outv;
#pragma unroll
        for (int mt = 0; mt < 4; mt++)
#pragma unroll
            for (int nt = 0; nt < 4; nt++)
#pragma unroll
                for (int r = 0; r < 4; r++) {
                    int m = m0 + wm * 64 + mt * 16 + quad * 4 + r;
                    int n = n0 + wn * 64 + nt * 16 + lane16;
                    out[(size_t)m * DD + n] = acc[mt][nt][r] + bias[n];
                }
    } else {
        int which = n0 >> 10;                       // block-uniform (128 | 1024)
        bf16* dst = (bf16*)outv + (size_t)which * MM * DD;
#pragma unroll
        for (int mt = 0; mt < 4; mt++)
#pragma unroll
            for (int nt = 0; nt < 4; nt++)
#pragma unroll
                for (int r = 0; r < 4; r++) {
                    int m = m0 + wm * 64 + mt * 16 + quad * 4 + r;
                    int n = n0 + wn * 64 + nt * 16 + lane16;
                    float v = acc[mt][nt][r] + bias[n];
                    int n1 = n & 1023;
                    int b = m >> 11, s = m & (SS - 1);
                    int h = n1 >> 6, dh = n1 & 63;
                    if (which < 2)
                        dst[((size_t)(b * HH + h) * SS + s) * DHH + dh] = (bf16)v;
                    else
                        dst[((size_t)(b * HH + h) * DHH + dh) * SS + s] = (bf16)v;
                }
    }
}

// ------------------------------------------------------------ attention (flash, no-max softmax)
// Q: [bh][s][dh] pre-scaled by 0.125*log2e   K: [bh][s][dh]   Vt: [bh][dh][s]
// ctx: [b][s][h*DH+dh] bf16
__global__ __launch_bounds__(256) void attn_k(const bf16* __restrict__ Q,
                                              const bf16* __restrict__ K,
                                              const bf16* __restrict__ Vt,
                                              bf16* __restrict__ ctx) {
    __shared__ __align__(16) bf16 qs[64 * 72];
    __shared__ __align__(16) bf16 ks[64 * 72];
    __shared__ __align__(16) bf16 vs[64 * 72];
    __shared__ __align__(16) bf16 ps[4][16 * 68];   // stride 68: conflict-free quads

    const int tid = threadIdx.x;
    const int l = tid & 63, w = tid >> 6;
    const int quad = l >> 4, lane16 = l & 15;
    const int qt = (SS / 64 - 1) - blockIdx.x;      // big blocks dispatch first
    const int bh = blockIdx.y;
    const int q0 = qt * 64;
    const bf16* Qp = Q  + (size_t)bh * SS * DHH;
    const bf16* Kp = K  + (size_t)bh * SS * DHH;
    const bf16* Vp = Vt + (size_t)bh * DHH * SS;

    const int row = tid >> 2, colc = (tid & 3) * 16;
    *(uint4*)(qs + row * 72 + colc)     = *(const uint4*)(Qp + (size_t)(q0 + row) * DHH + colc);
    *(uint4*)(qs + row * 72 + colc + 8) = *(const uint4*)(Qp + (size_t)(q0 + row) * DHH + colc + 8);
    __syncthreads();
    bf16x8 qf0 = *(const bf16x8*)(qs + (w * 16 + lane16) * 72 + quad * 8);
    bf16x8 qf1 = *(const bf16x8*)(qs + (w * 16 + lane16) * 72 + 32 + quad * 8);

    // prefetch kt=0 K/V into registers
    uint4 ka = *(const uint4*)(Kp + (size_t)row * DHH + colc);
    uint4 kb = *(const uint4*)(Kp + (size_t)row * DHH + colc + 8);
    uint4 va = *(const uint4*)(Vp + (size_t)row * SS + colc);
    uint4 vb = *(const uint4*)(Vp + (size_t)row * SS + colc + 8);

    floatx4 o_acc[4] = {};
    float l_part[4] = {0.f, 0.f, 0.f, 0.f};

    for (int kt = 0; kt <= qt; kt++) {
        __syncthreads();                            // prev iter's ks/vs reads done
        *(uint4*)(ks + row * 72 + colc)     = ka;
        *(uint4*)(ks + row * 72 + colc + 8) = kb;
        *(uint4*)(vs + row * 72 + colc)     = va;
        *(uint4*)(vs + row * 72 + colc + 8) = vb;
        if (kt < qt) {                              // prefetch next tile (latency hidden)
            const bf16* Kn = Kp + (size_t)(kt + 1) * 64 * DHH;
            const bf16* Vn = Vp + (kt + 1) * 64;
            ka = *(const uint4*)(Kn + (size_t)row * DHH + colc);
            kb = *(const uint4*)(Kn + (size_t)row * DHH + colc + 8);
            va = *(const uint4*)(Vn + (size_t)row * SS + colc);
            vb = *(const uint4*)(Vn + (size_t)row * SS + colc + 8);
        }
        __syncthreads();

        // QK^T -> log2-domain scores (scale pre-folded into Q)
        floatx4 sc[4] = {};
#pragma unroll
        for (int nb = 0; nb < 4; nb++) {
            bf16x8 b0 = *(const bf16x8*)(ks + (nb * 16 + lane16) * 72 + quad * 8);
            sc[nb] = __builtin_amdgcn_mfma_f32_16x16x32_bf16(qf0, b0, sc[nb], 0, 0, 0);
            bf16x8 b1 = *(const bf16x8*)(ks + (nb * 16 + lane16) * 72 + 32 + quad * 8);
            sc[nb] = __builtin_amdgcn_mfma_f32_16x16x32_bf16(qf1, b1, sc[nb], 0, 0, 0);
        }

        // p = exp2(score); mask only on the diagonal tile; per-lane l partials
        float p[4][4];
        if (kt == qt) {
#pragma unroll
            for (int nb = 0; nb < 4; nb++) {
                int key = nb * 16 + lane16;
#pragma unroll
                for (int r = 0; r < 4; r++) {
                    int qr = (w * 16 + quad * 4 + r);
                    float e = exp2f(sc[nb][r]);
                    e = (key <= qr) ? e : 0.f;
                    p[nb][r] = e;
                    l_part[r] += e;
                }
            }
        } else {
#pragma unroll
            for (int nb = 0; nb < 4; nb++)
#pragma unroll
                for (int r = 0; r < 4; r++) {
                    float e = exp2f(sc[nb][r]);
                    p[nb][r] = e;
                    l_part[r] += e;
                }
        }

        // C-layout -> A-layout via per-wave LDS round trip (no block barrier)
#pragma unroll
        for (int nb = 0; nb < 4; nb++)
#pragma unroll
            for (int r = 0; r < 4; r++)
                ps[w][(quad * 4 + r) * 68 + nb * 16 + lane16] = (bf16)p[nb][r];
        asm volatile("s_waitcnt lgkmcnt(0)" ::: "memory");

#pragma unroll
        for (int kk = 0; kk < 2; kk++) {
            bf16x8 af = *(const bf16x8*)(&ps[w][lane16 * 68 + kk * 32 + quad * 8]);
#pragma unroll
            for (int nb = 0; nb < 4; nb++) {
                bf16x8 br = *(const bf16x8*)(vs + (nb * 16 + lane16) * 72 + kk * 32 + quad * 8);
                o_acc[nb] = __builtin_amdgcn_mfma_f32_16x16x32_bf16(af, br, o_acc[nb], 0, 0, 0);
            }
        }
    }

    // one-time l reduction over the 16-lane column group
#pragma unroll
    for (int off = 1; off < 16; off <<= 1)
#pragma unroll
        for (int r = 0; r < 4; r++)
            l_part[r] += __shfl_xor(l_part[r], off, 64);

    int b = bh >> 4, h = bh & 15;
#pragma unroll
    for (int r = 0; r < 4; r++) {
        float inv = 1.0f / l_part[r];
        int s = q0 + w * 16 + quad * 4 + r;
#pragma unroll
        for (int nb = 0; nb < 4; nb++) {
            int dh = nb * 16 + lane16;
            ctx[((size_t)(b * SS + s)) * DD + h * DHH + dh] = (bf16)(o_acc[nb][r] * inv);
        }
    }
}

// ------------------------------------------------------------ launch
extern "C" void kernel_launch(void* const* d_in, const int* in_sizes, int n_in,
                              void* d_out, int out_size, void* d_ws, size_t ws_size,
                              hipStream_t stream) {
    const float* x  = (const float*)d_in[0];
    const float* Wq = (const float*)d_in[1];
    const float* bq = (const float*)d_in[2];
    const float* Wk = (const float*)d_in[3];
    const float* bk = (const float*)d_in[4];
    const float* Wv = (const float*)d_in[5];
    const float* bv = (const float*)d_in[6];
    const float* Wo = (const float*)d_in[7];
    const float* bo = (const float*)d_in[8];

    bf16* ws   = (bf16*)d_ws;
    bf16* xc   = ws;                               // 16 MB  x as bf16
    bf16* Wcat = xc + (size_t)MM * DD;             //  8 MB  [Wq^T*c | Wk^T | Wv^T | Wo^T]
    bf16* Qb   = Wcat + (size_t)4 * DD * DD;       // 16 MB each, contiguous Q|K|V
    bf16* Kb   = Qb + (size_t)MM * DD;
    bf16* Vb   = Kb + (size_t)MM * DD;
    bf16* Cb   = Vb + (size_t)MM * DD;             // 16 MB  context
    float* bcat = (float*)(Cb + (size_t)MM * DD);  // 12 KB

    cvt_k<<<dim3(MM * DD / 2048), dim3(256), 0, stream>>>(x, xc);
    transpose_k<<<dim3(16, 16, 4), dim3(256), 0, stream>>>(Wq, Wk, Wv, Wo, Wcat);
    bias_cat_k<<<dim3(12), dim3(256), 0, stream>>>(bq, bk, bv, bcat);

    gemm128_k<1><<<dim3(3 * DD / 128, MM / 128), dim3(256), 0, stream>>>(xc, Wcat, bcat, Qb);
    attn_k<<<dim3(SS / 64, BB * HH), dim3(256), 0, stream>>>(Qb, Kb, Vb, Cb);
    gemm128_k<0><<<dim3(DD / 128, MM / 128), dim3(256), 0, stream>>>(
        Cb, Wcat + (size_t)3 * DD * DD, bo, d_out);
}

// Round 7
// 350.301 us; speedup vs baseline: 1.6376x; 1.0529x over previous
//
#include <hip/hip_runtime.h>
#include <hip/hip_bf16.h>

#define BB 4
#define SS 2048
#define DD 1024
#define HH 16
#define DHH 64
#define MM (BB*SS)   // 8192

typedef __bf16 bf16;
typedef __attribute__((ext_vector_type(4))) __bf16 bf16x4;
typedef __attribute__((ext_vector_type(8))) __bf16 bf16x8;
typedef __attribute__((ext_vector_type(4))) float floatx4;

#define C_SCALE 0.1803368801111164f   // 0.125 * log2(e), folded into Wq/bq

// async global->LDS DMA, 16 B per lane, lands at wave-uniform base + lane*16
#define GLD16(g, l) __builtin_amdgcn_global_load_lds( \
    (__attribute__((address_space(1))) void*)(g), \
    (__attribute__((address_space(3))) void*)(l), 16, 0, 0)

// ------------------------------------------------------------ x f32 -> bf16
__global__ __launch_bounds__(256) void cvt_k(const float* __restrict__ x,
                                             bf16* __restrict__ xc) {
    size_t o = ((size_t)blockIdx.x * 256 + threadIdx.x) * 8;
    float4 f0 = *(const float4*)(x + o);
    float4 f1 = *(const float4*)(x + o + 4);
    bf16x8 v;
    v[0] = (bf16)f0.x; v[1] = (bf16)f0.y; v[2] = (bf16)f0.z; v[3] = (bf16)f0.w;
    v[4] = (bf16)f1.x; v[5] = (bf16)f1.y; v[6] = (bf16)f1.z; v[7] = (bf16)f1.w;
    *(bf16x8*)(xc + o) = v;
}

// ------------------------------------------------------------ transpose
// Wt[z][n][k] = (bf16)(W[k][n] * scale), scale folds C_SCALE into Wq (z==0)
__global__ void transpose_k(const float* __restrict__ W0, const float* __restrict__ W1,
                            const float* __restrict__ W2, const float* __restrict__ W3,
                            bf16* __restrict__ Wt) {
    __shared__ bf16 tile[64][65];
    const float* W = (blockIdx.z == 0) ? W0 : (blockIdx.z == 1) ? W1
                    : (blockIdx.z == 2) ? W2 : W3;
    float sc = (blockIdx.z == 0) ? C_SCALE : 1.0f;
    bf16* Wo = Wt + (size_t)blockIdx.z * DD * DD;
    int bx = blockIdx.x * 64, by = blockIdx.y * 64;
    int tx = threadIdx.x & 63, ty = threadIdx.x >> 6;
    for (int i = ty; i < 64; i += 4)
        tile[i][tx] = (bf16)(W[(size_t)(by + i) * DD + bx + tx] * sc);
    __syncthreads();
    for (int i = ty; i < 64; i += 4)
        Wo[(size_t)(bx + i) * DD + by + tx] = tile[tx][i];
}

// ------------------------------------------------------------ bias concat (scale bq)
__global__ void bias_cat_k(const float* __restrict__ bq, const float* __restrict__ bk,
                           const float* __restrict__ bv, float* __restrict__ bcat) {
    int i = blockIdx.x * 256 + threadIdx.x;
    float v;
    if (i < 1024)      v = bq[i] * C_SCALE;
    else if (i < 2048) v = bk[i - 1024];
    else               v = bv[i - 2048];
    bcat[i] = v;
}

// ------------------------------------------------------------ 128x128 GEMM (m97 structure)
// out = A[m][k] * Bt[n][k] + bias[n]
// MODE 0: float out[m*DD+n]
// MODE 1: fused QKV routing; out base of contiguous Qb|Kb|Vb; block-uniform which=n0>>10
//   Q,K: bf16 [((b*H+h)*S+s)*DH+dh]
//   V:   bf16 [((b*H+h)*DH+dh)*S + sigma(s)]  sigma = 4*(s&15)+((s>>4)&3) within 64-tile
template<int MODE>
__global__ __launch_bounds__(256) void gemm128_k(const bf16* __restrict__ A,
                                                 const bf16* __restrict__ Bt,
                                                 const float* __restrict__ bias,
                                                 void* __restrict__ outv) {
    __shared__ __align__(16) bf16 la[128 * 32];
    __shared__ __align__(16) bf16 lb[128 * 32];
    const int tid = threadIdx.x;
    const int l = tid & 63, w = tid >> 6;
    const int quad = l >> 4, lane16 = l & 15;
    const int wm = w >> 1, wn = w & 1;
    const int m0 = blockIdx.y * 128, n0 = blockIdx.x * 128;

    const int sr  = l >> 2;
    const int sc8 = (l & 3) * 8;
    const bf16* Ag0 = A  + (size_t)(m0 + w * 16 + sr) * DD + sc8;
    const bf16* Ag1 = A  + (size_t)(m0 + (4 + w) * 16 + sr) * DD + sc8;
    const bf16* Bg0 = Bt + (size_t)(n0 + w * 16 + sr) * DD + sc8;
    const bf16* Bg1 = Bt + (size_t)(n0 + (4 + w) * 16 + sr) * DD + sc8;
    bf16* Al0 = la + (size_t)(w * 16 + sr) * 32 + sc8;
    bf16* Al1 = la + (size_t)((4 + w) * 16 + sr) * 32 + sc8;
    bf16* Bl0 = lb + (size_t)(w * 16 + sr) * 32 + sc8;
    bf16* Bl1 = lb + (size_t)((4 + w) * 16 + sr) * 32 + sc8;

    floatx4 acc[4][4] = {};
    for (int k0 = 0; k0 < DD; k0 += 32) {
        __syncthreads();
        GLD16(Ag0 + k0, Al0);
        GLD16(Ag1 + k0, Al1);
        GLD16(Bg0 + k0, Bl0);
        GLD16(Bg1 + k0, Bl1);
        __syncthreads();
        bf16x8 af[4], bfr[4];
#pragma unroll
        for (int mt = 0; mt < 4; mt++)
            af[mt] = *(const bf16x8*)(la + (size_t)(wm * 64 + mt * 16 + lane16) * 32 + quad * 8);
#pragma unroll
        for (int nt = 0; nt < 4; nt++)
            bfr[nt] = *(const bf16x8*)(lb + (size_t)(wn * 64 + nt * 16 + lane16) * 32 + quad * 8);
#pragma unroll
        for (int mt = 0; mt < 4; mt++)
#pragma unroll
            for (int nt = 0; nt < 4; nt++)
                acc[mt][nt] = __builtin_amdgcn_mfma_f32_16x16x32_bf16(af[mt], bfr[nt], acc[mt][nt], 0, 0, 0);
    }

    if (MODE == 0) {
        float* out = (float*)outv;
#pragma unroll
        for (int mt = 0; mt < 4; mt++)
#pragma unroll
            for (int nt = 0; nt < 4; nt++)
#pragma unroll
                for (int r = 0; r < 4; r++) {
                    int m = m0 + wm * 64 + mt * 16 + quad * 4 + r;
                    int n = n0 + wn * 64 + nt * 16 + lane16;
                    out[(size_t)m * DD + n] = acc[mt][nt][r] + bias[n];
                }
    } else {
        int which = n0 >> 10;
        bf16* dst = (bf16*)outv + (size_t)which * MM * DD;
#pragma unroll
        for (int mt = 0; mt < 4; mt++)
#pragma unroll
            for (int nt = 0; nt < 4; nt++)
#pragma unroll
                for (int r = 0; r < 4; r++) {
                    int m = m0 + wm * 64 + mt * 16 + quad * 4 + r;
                    int n = n0 + wn * 64 + nt * 16 + lane16;
                    float v = acc[mt][nt][r] + bias[n];
                    int n1 = n & 1023;
                    int b = m >> 11, s = m & (SS - 1);
                    int h = n1 >> 6, dh = n1 & 63;
                    if (which < 2) {
                        dst[((size_t)(b * HH + h) * SS + s) * DHH + dh] = (bf16)v;
                    } else {
                        int st = s & 63;
                        int sp = (s & ~63) | ((st & 15) * 4 + (st >> 4));   // sigma for packed P-store
                        dst[((size_t)(b * HH + h) * DHH + dh) * SS + sp] = (bf16)v;
                    }
                }
    }
}

// ------------------------------------------------------------ attention
// 128 queries/block, 32/wave (2 subtiles). K-tile 64 keys.
// Q: [bh][s][dh] pre-scaled by 0.125*log2e   K: [bh][s][dh]
// Vt: [bh][dh][sigma(s)] (sigma within 64-tiles)   ctx: [b][s][h*DH+dh]
__global__ __launch_bounds__(256, 2) void attn_k(const bf16* __restrict__ Q,
                                                 const bf16* __restrict__ K,
                                                 const bf16* __restrict__ Vt,
                                                 bf16* __restrict__ ctx) {
    __shared__ __align__(16) bf16 ks[64 * 72];
    __shared__ __align__(16) bf16 vs[64 * 72];
    __shared__ __align__(16) bf16 ps[4][16 * 72];

    const int tid = threadIdx.x;
    const int l = tid & 63, w = tid >> 6;
    const int quad = l >> 4, lane16 = l & 15;
    const int qt = (SS / 128 - 1) - blockIdx.x;    // big blocks dispatch first
    const int bh = blockIdx.y;
    const int q0 = qt * 128;
    const bf16* Qp = Q  + (size_t)bh * SS * DHH;
    const bf16* Kp = K  + (size_t)bh * SS * DHH;
    const bf16* Vp = Vt + (size_t)bh * DHH * SS;

    // Q A-frags straight from global (one-time, 64B segments per row)
    bf16x8 qf[2][2];
#pragma unroll
    for (int sub = 0; sub < 2; sub++)
#pragma unroll
        for (int kk = 0; kk < 2; kk++)
            qf[sub][kk] = *(const bf16x8*)(
                Qp + (size_t)(q0 + w * 32 + sub * 16 + lane16) * DHH + kk * 32 + quad * 8);

    const int row = tid >> 2, colc = (tid & 3) * 16;
    uint4 ka = *(const uint4*)(Kp + (size_t)row * DHH + colc);
    uint4 kb = *(const uint4*)(Kp + (size_t)row * DHH + colc + 8);
    uint4 va = *(const uint4*)(Vp + (size_t)row * SS + colc);
    uint4 vb = *(const uint4*)(Vp + (size_t)row * SS + colc + 8);

    floatx4 o_acc[2][4] = {};
    float l_part[2][4] = {};

    const int nkt = 2 * qt + 2;
    for (int kt = 0; kt < nkt; kt++) {
        __syncthreads();
        *(uint4*)(ks + row * 72 + colc)     = ka;
        *(uint4*)(ks + row * 72 + colc + 8) = kb;
        *(uint4*)(vs + row * 72 + colc)     = va;
        *(uint4*)(vs + row * 72 + colc + 8) = vb;
        if (kt + 1 < nkt) {
            const bf16* Kn = Kp + (size_t)(kt + 1) * 64 * DHH;
            const bf16* Vn = Vp + (kt + 1) * 64;
            ka = *(const uint4*)(Kn + (size_t)row * DHH + colc);
            kb = *(const uint4*)(Kn + (size_t)row * DHH + colc + 8);
            va = *(const uint4*)(Vn + (size_t)row * SS + colc);
            vb = *(const uint4*)(Vn + (size_t)row * SS + colc + 8);
        }
        __syncthreads();

        // cache all K/V fragments once (reused by both subtiles)
        bf16x8 kf[2][4], vf[2][4];
#pragma unroll
        for (int kk = 0; kk < 2; kk++)
#pragma unroll
            for (int nb = 0; nb < 4; nb++) {
                kf[kk][nb] = *(const bf16x8*)(ks + (nb * 16 + lane16) * 72 + kk * 32 + quad * 8);
                vf[kk][nb] = *(const bf16x8*)(vs + (nb * 16 + lane16) * 72 + kk * 32 + quad * 8);
            }

        const int kb0 = kt * 64;
#pragma unroll
        for (int sub = 0; sub < 2; sub++) {
            const int qsb = q0 + w * 32 + sub * 16;     // subtile min query (global)
            if (kb0 > qsb + 15) continue;               // fully masked (wave-uniform)

            floatx4 sc[4] = {};
#pragma unroll
            for (int nb = 0; nb < 4; nb++) {
                sc[nb] = __builtin_amdgcn_mfma_f32_16x16x32_bf16(qf[sub][0], kf[0][nb], sc[nb], 0, 0, 0);
                sc[nb] = __builtin_amdgcn_mfma_f32_16x16x32_bf16(qf[sub][1], kf[1][nb], sc[nb], 0, 0, 0);
            }

            float p[4][4];
            if (kb0 + 63 > qsb) {                       // diagonal: per-element mask
#pragma unroll
                for (int nb = 0; nb < 4; nb++) {
                    int key = kb0 + nb * 16 + lane16;
#pragma unroll
                    for (int r = 0; r < 4; r++) {
                        int qg = qsb + quad * 4 + r;
                        float e = exp2f(sc[nb][r]);
                        e = (key <= qg) ? e : 0.f;
                        p[nb][r] = e;
                        l_part[sub][r] += e;
                    }
                }
            } else {
#pragma unroll
                for (int nb = 0; nb < 4; nb++)
#pragma unroll
                    for (int r = 0; r < 4; r++) {
                        float e = exp2f(sc[nb][r]);
                        p[nb][r] = e;
                        l_part[sub][r] += e;
                    }
            }

            // packed P-store: column sigma(key)=4*lane16+nb -> one b64 per row
#pragma unroll
            for (int r = 0; r < 4; r++) {
                bf16x4 pk;
                pk[0] = (bf16)p[0][r]; pk[1] = (bf16)p[1][r];
                pk[2] = (bf16)p[2][r]; pk[3] = (bf16)p[3][r];
                *(bf16x4*)(&ps[w][(quad * 4 + r) * 72 + lane16 * 4]) = pk;
            }
            asm volatile("s_waitcnt lgkmcnt(0)" ::: "memory");

#pragma unroll
            for (int kk = 0; kk < 2; kk++) {
                bf16x8 af = *(const bf16x8*)(&ps[w][lane16 * 72 + kk * 32 + quad * 8]);
#pragma unroll
                for (int nb = 0; nb < 4; nb++)
                    o_acc[sub][nb] = __builtin_amdgcn_mfma_f32_16x16x32_bf16(af, vf[kk][nb], o_acc[sub][nb], 0, 0, 0);
            }
        }
    }

#pragma unroll
    for (int off = 1; off < 16; off <<= 1)
#pragma unroll
        for (int sub = 0; sub < 2; sub++)
#pragma unroll
            for (int r = 0; r < 4; r++)
                l_part[sub][r] += __shfl_xor(l_part[sub][r], off, 64);

    int b = bh >> 4, h = bh & 15;
#pragma unroll
    for (int sub = 0; sub < 2; sub++)
#pragma unroll
        for (int r = 0; r < 4; r++) {
            float inv = 1.0f / l_part[sub][r];
            int s = q0 + w * 32 + sub * 16 + quad * 4 + r;
#pragma unroll
            for (int nb = 0; nb < 4; nb++) {
                int dh = nb * 16 + lane16;
                ctx[((size_t)(b * SS + s)) * DD + h * DHH + dh] = (bf16)(o_acc[sub][nb][r] * inv);
            }
        }
}

// ------------------------------------------------------------ launch
extern "C" void kernel_launch(void* const* d_in, const int* in_sizes, int n_in,
                              void* d_out, int out_size, void* d_ws, size_t ws_size,
                              hipStream_t stream) {
    const float* x  = (const float*)d_in[0];
    const float* Wq = (const float*)d_in[1];
    const float* bq = (const float*)d_in[2];
    const float* Wk = (const float*)d_in[3];
    const float* bk = (const float*)d_in[4];
    const float* Wv = (const float*)d_in[5];
    const float* bv = (const float*)d_in[6];
    const float* Wo = (const float*)d_in[7];
    const float* bo = (const float*)d_in[8];

    bf16* ws   = (bf16*)d_ws;
    bf16* xc   = ws;                               // 16 MB  x as bf16
    bf16* Wcat = xc + (size_t)MM * DD;             //  8 MB  [Wq^T*c | Wk^T | Wv^T | Wo^T]
    bf16* Qb   = Wcat + (size_t)4 * DD * DD;       // 16 MB each, contiguous Q|K|V
    bf16* Kb   = Qb + (size_t)MM * DD;
    bf16* Vb   = Kb + (size_t)MM * DD;
    bf16* Cb   = Vb + (size_t)MM * DD;             // 16 MB  context
    float* bcat = (float*)(Cb + (size_t)MM * DD);  // 12 KB

    cvt_k<<<dim3(MM * DD / 2048), dim3(256), 0, stream>>>(x, xc);
    transpose_k<<<dim3(16, 16, 4), dim3(256), 0, stream>>>(Wq, Wk, Wv, Wo, Wcat);
    bias_cat_k<<<dim3(12), dim3(256), 0, stream>>>(bq, bk, bv, bcat);

    gemm128_k<1><<<dim3(3 * DD / 128, MM / 128), dim3(256), 0, stream>>>(xc, Wcat, bcat, Qb);
    attn_k<<<dim3(SS / 128, BB * HH), dim3(256), 0, stream>>>(Qb, Kb, Vb, Cb);
    gemm128_k<0><<<dim3(DD / 128, MM / 128), dim3(256), 0, stream>>>(
        Cb, Wcat + (size_t)3 * DD * DD, bo, d_out);
}